// Round 2
// baseline (1497.894 us; speedup 1.0000x reference)
//
#include <hip/hip_runtime.h>
#include <cstdint>
#include <cstddef>

#define TLEN 512
#define BATCH 1000
#define NEVS 102400   // events per source
#define HID 64

__device__ __forceinline__ float fast_rcp(float x) {
#if __has_builtin(__builtin_amdgcn_rcpf)
    return __builtin_amdgcn_rcpf(x);
#else
    return 1.0f / x;
#endif
}
__device__ __forceinline__ float sigm(float x) { return fast_rcp(1.0f + __expf(-x)); }
__device__ __forceinline__ float tanh_f(float x) { return fmaf(2.0f, sigm(2.0f * x), -1.0f); }

// Wave-wide sum broadcast (rocPRIM gfx9 DPP pattern), ~40 cy vs ~200 for shfl chain.
__device__ __forceinline__ float wave_sum_bcast(float x) {
#if __has_builtin(__builtin_amdgcn_update_dpp) && __has_builtin(__builtin_amdgcn_readlane)
    x += __int_as_float(__builtin_amdgcn_update_dpp(0, __float_as_int(x), 0x111, 0xf, 0xf, true)); // row_shr:1
    x += __int_as_float(__builtin_amdgcn_update_dpp(0, __float_as_int(x), 0x112, 0xf, 0xf, true)); // row_shr:2
    x += __int_as_float(__builtin_amdgcn_update_dpp(0, __float_as_int(x), 0x114, 0xf, 0xf, true)); // row_shr:4
    x += __int_as_float(__builtin_amdgcn_update_dpp(0, __float_as_int(x), 0x118, 0xf, 0xf, true)); // row_shr:8
    x += __int_as_float(__builtin_amdgcn_update_dpp(0, __float_as_int(x), 0x142, 0xa, 0xf, true)); // row_bcast:15
    x += __int_as_float(__builtin_amdgcn_update_dpp(0, __float_as_int(x), 0x143, 0xc, 0xf, true)); // row_bcast:31
    return __int_as_float(__builtin_amdgcn_readlane(__float_as_int(x), 63));
#else
#pragma unroll
    for (int off = 1; off < 64; off <<= 1) x += __shfl_xor(x, off, 64);
    return x;
#endif
}

// ===========================================================================
// Event binning by ti: count -> scan -> scatter. Run once; makes every time
// chunk's event set a contiguous range of `order` per source.
// ===========================================================================
__global__ __launch_bounds__(256) void bin_zero_kernel(int* __restrict__ cnt)
{
    int i = blockIdx.x * 256 + threadIdx.x;
    if (i < 5 * 512) cnt[i] = 0;
}

__global__ __launch_bounds__(256) void bin_count_kernel(
    const int* __restrict__ t0, const int* __restrict__ t1,
    const int* __restrict__ t2, const int* __restrict__ t3,
    const int* __restrict__ t4, int* __restrict__ cnt)
{
    const int src = blockIdx.y;
    const int* ti = src == 0 ? t0 : src == 1 ? t1 : src == 2 ? t2 : src == 3 ? t3 : t4;
    const int e = blockIdx.x * 256 + threadIdx.x;
    atomicAdd(&cnt[src * 512 + ti[e]], 1);
}

__global__ __launch_bounds__(512) void bin_scan_kernel(
    const int* __restrict__ cnt, int* __restrict__ startp, int* __restrict__ cur)
{
    const int src = blockIdx.x, tid = threadIdx.x;
    __shared__ int s[512];
    const int v = cnt[src * 512 + tid];
    s[tid] = v;
    __syncthreads();
    for (int off = 1; off < 512; off <<= 1) {
        int t = (tid >= off) ? s[tid - off] : 0;
        __syncthreads();
        s[tid] += t;
        __syncthreads();
    }
    const int inc = s[tid];
    startp[src * 513 + tid] = inc - v;
    cur[src * 512 + tid] = inc - v;
    if (tid == 511) startp[src * 513 + 512] = inc;
}

__global__ __launch_bounds__(256) void bin_scatter_kernel(
    const int* __restrict__ t0, const int* __restrict__ t1,
    const int* __restrict__ t2, const int* __restrict__ t3,
    const int* __restrict__ t4, int* __restrict__ cur, int* __restrict__ order)
{
    const int src = blockIdx.y;
    const int* ti = src == 0 ? t0 : src == 1 ? t1 : src == 2 ? t2 : src == 3 ? t3 : t4;
    const int e = blockIdx.x * 256 + threadIdx.x;
    const int off = atomicAdd(&cur[src * 512 + ti[e]], 1);
    order[(size_t)src * NEVS + off] = e;
}

// ===========================================================================
// Composed projection weights: W'[row][col], row=(src,j) [130], col=dir*256+r.
// ===========================================================================
__global__ __launch_bounds__(512) void compose_kernel(
    const float* __restrict__ W0, const float* __restrict__ B0,
    const float* __restrict__ W1, const float* __restrict__ B1,
    const float* __restrict__ W2, const float* __restrict__ B2,
    const float* __restrict__ W3, const float* __restrict__ B3,
    const float* __restrict__ W4, const float* __restrict__ B4,
    const float* __restrict__ Wih, const float* __restrict__ bih,
    const float* __restrict__ bhh, float* __restrict__ wp)
{
    const int col = threadIdx.x;   // 0..511 == dir*256 + r == Wih row index
    const int row = blockIdx.x;    // 0..129
    const float* srcW; const float* srcB; int base, IND;
    if (row < 9)        { srcW = W0; srcB = B0; base = 0;   IND = 8;  }
    else if (row < 27)  { srcW = W1; srcB = B1; base = 9;   IND = 17; }
    else if (row < 53)  { srcW = W2; srcB = B2; base = 27;  IND = 25; }
    else if (row < 120) { srcW = W3; srcB = B3; base = 53;  IND = 66; }
    else                { srcW = W4; srcB = B4; base = 120; IND = 9;  }
    const int j = row - base;
    const float* xrow = (j < IND) ? (srcW + (size_t)j * 64) : srcB;
    const float* wr = Wih + (size_t)col * 64;
    float acc = 0.0f;
#pragma unroll
    for (int h2 = 0; h2 < 64; ++h2) acc = fmaf(xrow[h2], wr[h2], acc);
    if (j == IND) acc += bih[col] + bhh[col];
    wp[(size_t)row * 512 + col] = acc;
}

// ===========================================================================
// Projection for one chunk: events come from the binned contiguous range
// [start[lo], start[hi]) of `order`; 4 events in flight, no queue, no atomics.
// ===========================================================================
template<int NNUM, int NCAT>
__device__ __forceinline__ void project_src(
    const float* __restrict__ num, const int* __restrict__ cat,
    const float* __restrict__ tab, const int* __restrict__ bi,
    const int* __restrict__ ti, const float* __restrict__ wrows,
    const int* __restrict__ order_s, const int* __restrict__ start_s,
    float* __restrict__ gdst, int dir, int lo, int hi, int tcm)
{
    constexpr int IND = NCAT * 8 + NNUM;
    const int tid = threadIdx.x;
    const int col = dir * 256 + tid;
    float wcol[IND];
#pragma unroll
    for (int j = 0; j < IND; ++j) wcol[j] = wrows[(size_t)j * 512 + col];
    const float bcol = wrows[(size_t)IND * 512 + col];

    const int r0 = start_s[lo];
    const int r1 = start_s[hi];

    for (int i = r0 + (int)blockIdx.x * 4; i < r1; i += (int)gridDim.x * 4) {
        int ebuf[4], tE[4], pE[4];
#pragma unroll
        for (int k = 0; k < 4; ++k) {
            const int j = i + k;
            ebuf[k] = __builtin_amdgcn_readfirstlane(order_s[(j < r1) ? j : i]);
        }
#pragma unroll
        for (int k = 0; k < 4; ++k) { tE[k] = ti[ebuf[k]]; pE[k] = bi[ebuf[k]]; }

        float acc[4] = {bcol, bcol, bcol, bcol};
#pragma unroll
        for (int c0 = 0; c0 < NCAT; ++c0) {
            const float* t0 = tab + (size_t)cat[ebuf[0] * NCAT + c0] * 8;
            const float* t1 = tab + (size_t)cat[ebuf[1] * NCAT + c0] * 8;
            const float* t2 = tab + (size_t)cat[ebuf[2] * NCAT + c0] * 8;
            const float* t3 = tab + (size_t)cat[ebuf[3] * NCAT + c0] * 8;
#pragma unroll
            for (int u = 0; u < 8; ++u) {
                const float w = wcol[c0 * 8 + u];
                acc[0] = fmaf(t0[u], w, acc[0]);
                acc[1] = fmaf(t1[u], w, acc[1]);
                acc[2] = fmaf(t2[u], w, acc[2]);
                acc[3] = fmaf(t3[u], w, acc[3]);
            }
        }
#pragma unroll
        for (int u = 0; u < NNUM; ++u) {
            const float w = wcol[NCAT * 8 + u];
            acc[0] = fmaf(num[(size_t)ebuf[0] * NNUM + u], w, acc[0]);
            acc[1] = fmaf(num[(size_t)ebuf[1] * NNUM + u], w, acc[1]);
            acc[2] = fmaf(num[(size_t)ebuf[2] * NNUM + u], w, acc[2]);
            acc[3] = fmaf(num[(size_t)ebuf[3] * NNUM + u], w, acc[3]);
        }
#pragma unroll
        for (int k = 0; k < 4; ++k) {
            if (i + k < r1) {
                const int l = dir ? (hi - 1 - tE[k]) : (tE[k] - lo);
                gdst[((size_t)pE[k] * tcm + l) * 256 + tid] = acc[k];
            }
        }
    }
}

__global__ __launch_bounds__(256) void project_chunk_kernel(
    const float* __restrict__ ccba_num, const int* __restrict__ ccba_bi, const int* __restrict__ ccba_ti,
    const float* __restrict__ cdtx_num, const int* __restrict__ cdtx_cat, const float* __restrict__ cdtx_tab,
    const int* __restrict__ cdtx_bi, const int* __restrict__ cdtx_ti,
    const float* __restrict__ cust_num, const int* __restrict__ cust_cat, const float* __restrict__ cust_tab,
    const int* __restrict__ cust_bi, const int* __restrict__ cust_ti,
    const float* __restrict__ dp_num, const int* __restrict__ dp_cat, const float* __restrict__ dp_tab,
    const int* __restrict__ dp_bi, const int* __restrict__ dp_ti,
    const float* __restrict__ remit_num, const int* __restrict__ remit_cat, const float* __restrict__ remit_tab,
    const int* __restrict__ remit_bi, const int* __restrict__ remit_ti,
    const float* __restrict__ wp, const int* __restrict__ order, const int* __restrict__ startp,
    float* __restrict__ gf, float* __restrict__ gb,
    int f0, int len, int tcm)
{
    const int dir = blockIdx.y & 1;
    const int src = blockIdx.y >> 1;
    const int lo = dir ? (TLEN - f0 - len) : f0;   // bwd chunk is the mirrored range
    const int hi = lo + len;
    float* gdst = dir ? gb : gf;
    const int* order_s = order + (size_t)src * NEVS;
    const int* start_s = startp + src * 513;
    switch (src) {
        case 0: project_src<8, 0>(ccba_num, nullptr, nullptr, ccba_bi, ccba_ti, wp + 0 * 512,   order_s, start_s, gdst, dir, lo, hi, tcm); break;
        case 1: project_src<1, 2>(cdtx_num, cdtx_cat, cdtx_tab, cdtx_bi, cdtx_ti, wp + 9 * 512,  order_s, start_s, gdst, dir, lo, hi, tcm); break;
        case 2: project_src<1, 3>(cust_num, cust_cat, cust_tab, cust_bi, cust_ti, wp + 27 * 512, order_s, start_s, gdst, dir, lo, hi, tcm); break;
        case 3: project_src<2, 8>(dp_num,   dp_cat,   dp_tab,   dp_bi,   dp_ti,   wp + 53 * 512, order_s, start_s, gdst, dir, lo, hi, tcm); break;
        default: project_src<1, 1>(remit_num, remit_cat, remit_tab, remit_bi, remit_ti, wp + 120 * 512, order_s, start_s, gdst, dir, lo, hi, tcm); break;
    }
}

// ===========================================================================
// Layer-0 recurrence over the precomputed chunk: one wave per (b,dir),
// lane = cell; 2-step gate prefetch; (h,c) carried across chunk launches.
// ===========================================================================
__global__ __launch_bounds__(256) void rec_chunk_kernel(
    const float* __restrict__ gf, const float* __restrict__ gb,
    const float* __restrict__ Whh, const float* __restrict__ Whr,
    float* __restrict__ h0, float* __restrict__ hs, float* __restrict__ cs,
    int f0, int len, int tcm, int first)
{
    const int wv = threadIdx.x >> 6, lane = threadIdx.x & 63;
    const int p = blockIdx.x * 4 + wv;          // 0..1999
    const int b = p >> 1, dir = p & 1;

    float whh4[4];
#pragma unroll
    for (int k = 0; k < 4; ++k) whh4[k] = Whh[dir * 256 + k * 64 + lane];
    const float whr = Whr[dir * HID + lane];

    const float* g = (dir ? gb : gf) + (size_t)b * tcm * 256 + lane;
    float* h0p = h0 + (size_t)b * TLEN * 2 + dir;

    float h, c;
    if (first) { h = 0.0f; c = 0.0f; }
    else       { h = hs[p]; c = cs[(size_t)p * 64 + lane]; }

    auto ga = [&](int s) -> const float* {
        const int sc = (s < len) ? s : (len - 1);   // clamp; value unused past end
        return g + (size_t)sc * 256;
    };
    auto do_step = [&](const float (&G)[4], int s) {
        const float gi = fmaf(whh4[0], h, G[0]);
        const float gfv = fmaf(whh4[1], h, G[1]);
        const float gg = fmaf(whh4[2], h, G[2]);
        const float go = fmaf(whh4[3], h, G[3]);
        c = sigm(gfv) * c + sigm(gi) * tanh_f(gg);
        h = wave_sum_bcast(sigm(go) * tanh_f(c) * whr);
        const int t_out = dir ? (TLEN - 1 - f0 - s) : (f0 + s);
        if (lane == 0) h0p[(size_t)t_out * 2] = h;
    };

    float A[4], B[4];
    {
        const float* pa = ga(0); const float* pb = ga(1);
#pragma unroll
        for (int k = 0; k < 4; ++k) { A[k] = pa[k * 64]; B[k] = pb[k * 64]; }
    }
    for (int s = 0; s < len; s += 2) {
        float C[4], D[4];
        const float* pc = ga(s + 2); const float* pd = ga(s + 3);
#pragma unroll
        for (int k = 0; k < 4; ++k) { C[k] = pc[k * 64]; D[k] = pd[k * 64]; }
        do_step(A, s);
        if (s + 1 < len) do_step(B, s + 1);
#pragma unroll
        for (int k = 0; k < 4; ++k) { A[k] = C[k]; B[k] = D[k]; }
    }
    if (lane == 0) hs[p] = h;
    cs[(size_t)p * 64 + lane] = c;
}

// ===========================================================================
// LSTM layer 1 (insz=2), 2-step x prefetch. One wave per (b,dir). DPP reduce.
// ===========================================================================
__global__ __launch_bounds__(256) void lstm1_kernel(
    const float* __restrict__ h0, const float* __restrict__ Wih,
    const float* __restrict__ Whh, const float* __restrict__ Whr,
    const float* __restrict__ bih, const float* __restrict__ bhh,
    float* __restrict__ h1)
{
    int w = threadIdx.x >> 6, lane = threadIdx.x & 63;
    int p = blockIdx.x * 4 + w;
    int b = p >> 1, dir = p & 1;

    float wi0[4], wi1[4], whh[4], bias[4];
#pragma unroll
    for (int k = 0; k < 4; ++k) {
        int r = k * 64 + lane;
        wi0[k] = Wih[(size_t)(dir * 256 + r) * 2 + 0];
        wi1[k] = Wih[(size_t)(dir * 256 + r) * 2 + 1];
        whh[k] = Whh[dir * 256 + r];
        bias[k] = bih[dir * 256 + r] + bhh[dir * 256 + r];
    }
    float whr = Whr[dir * HID + lane];
    float h = 0.0f, c = 0.0f;
    const float* hb = h0 + (size_t)b * TLEN * 2;

    auto xat = [&](int t) -> float2 {
        int tc = t < TLEN ? t : TLEN - 1;
        int tt = dir ? (TLEN - 1 - tc) : tc;
        return *(const float2*)(hb + (size_t)tt * 2);
    };

    float2 xA = xat(0), xB = xat(1);
    for (int t = 0; t < TLEN; t += 2) {
        float2 xC = xat(t + 2), xD = xat(t + 3);
        {
            float g[4];
#pragma unroll
            for (int k = 0; k < 4; ++k)
                g[k] = fmaf(whh[k], h, fmaf(wi1[k], xA.y, fmaf(wi0[k], xA.x, bias[k])));
            c = sigm(g[1]) * c + sigm(g[0]) * tanh_f(g[2]);
            h = wave_sum_bcast(sigm(g[3]) * tanh_f(c) * whr);
            int tt = dir ? (TLEN - 1 - t) : t;
            if (lane == 0) h1[((size_t)b * TLEN + tt) * 2 + dir] = h;
        }
        {
            float g[4];
#pragma unroll
            for (int k = 0; k < 4; ++k)
                g[k] = fmaf(whh[k], h, fmaf(wi1[k], xB.y, fmaf(wi0[k], xB.x, bias[k])));
            c = sigm(g[1]) * c + sigm(g[0]) * tanh_f(g[2]);
            h = wave_sum_bcast(sigm(g[3]) * tanh_f(c) * whr);
            int tt = dir ? (TLEN - 2 - t) : (t + 1);
            if (lane == 0) h1[((size_t)b * TLEN + tt) * 2 + dir] = h;
        }
        xA = xC; xB = xD;
    }
}

__global__ __launch_bounds__(256) void mean_kernel(
    const float2* __restrict__ h1, float* __restrict__ out)
{
    int i = blockIdx.x * 256 + threadIdx.x;
    if (i < BATCH * TLEN) {
        float2 v = h1[i];
        out[i] = 0.5f * (v.x + v.y);
    }
}

// ===========================================================================
extern "C" void kernel_launch(void* const* d_in, const int* in_sizes, int n_in,
                              void* d_out, int out_size, void* d_ws, size_t ws_size,
                              hipStream_t stream)
{
    const float* ccba_num = (const float*)d_in[0];
    const int*   ccba_bi  = (const int*)d_in[1];
    const int*   ccba_ti  = (const int*)d_in[2];
    const float* ccba_W   = (const float*)d_in[3];
    const float* ccba_b   = (const float*)d_in[4];
    const float* cdtx_num = (const float*)d_in[5];
    const int*   cdtx_cat = (const int*)d_in[6];
    const float* cdtx_tab = (const float*)d_in[7];
    const int*   cdtx_bi  = (const int*)d_in[8];
    const int*   cdtx_ti  = (const int*)d_in[9];
    const float* cdtx_W   = (const float*)d_in[10];
    const float* cdtx_b   = (const float*)d_in[11];
    const float* cust_num = (const float*)d_in[12];
    const int*   cust_cat = (const int*)d_in[13];
    const float* cust_tab = (const float*)d_in[14];
    const int*   cust_bi  = (const int*)d_in[15];
    const int*   cust_ti  = (const int*)d_in[16];
    const float* cust_W   = (const float*)d_in[17];
    const float* cust_b   = (const float*)d_in[18];
    const float* dp_num   = (const float*)d_in[19];
    const int*   dp_cat   = (const int*)d_in[20];
    const float* dp_tab   = (const float*)d_in[21];
    const int*   dp_bi    = (const int*)d_in[22];
    const int*   dp_ti    = (const int*)d_in[23];
    const float* dp_W     = (const float*)d_in[24];
    const float* dp_b     = (const float*)d_in[25];
    const float* remit_num = (const float*)d_in[26];
    const int*   remit_cat = (const int*)d_in[27];
    const float* remit_tab = (const float*)d_in[28];
    const int*   remit_bi  = (const int*)d_in[29];
    const int*   remit_ti  = (const int*)d_in[30];
    const float* remit_W   = (const float*)d_in[31];
    const float* remit_b   = (const float*)d_in[32];
    const float* Wih0 = (const float*)d_in[33];
    const float* Whh0 = (const float*)d_in[34];
    const float* Whr0 = (const float*)d_in[35];
    const float* bih0 = (const float*)d_in[36];
    const float* bhh0 = (const float*)d_in[37];
    const float* Wih1 = (const float*)d_in[38];
    const float* Whh1 = (const float*)d_in[39];
    const float* Whr1 = (const float*)d_in[40];
    const float* bih1 = (const float*)d_in[41];
    const float* bhh1 = (const float*)d_in[42];

    float* out = (float*)d_out;

    // Workspace layout:
    //   gf, gb : 1000 * tcm * 256 * 4 each (chunk gate pre-activations)
    //   h0, h1 : 4,096,000 each
    //   wp     : 266,240
    //   hs     : 8,000        cs : 512,000
    //   order  : 5*102400*4 = 2,048,000
    //   cnt    : 10,240   start : 10,272 (513*5*4 padded)   cur : 10,240
    const size_t FIXED = 4096000ull + 4096000ull + 266240ull + 8000ull + 512000ull
                       + 2048000ull + 10240ull + 10272ull + 10240ull;
    size_t avail = (ws_size > FIXED) ? (ws_size - FIXED) : 0;
    int tcm = (int)(avail / 2048000ull);
    if (tcm < 1) tcm = 1;
    if (tcm > 86) tcm = 86;          // keep gf+gb (<=176 MB) + state L3-resident
    if (tcm >= 2) tcm &= ~1;         // even -> even len every chunk

    char* ws = (char*)d_ws;
    const size_t gfB = (size_t)tcm * 1024000ull;
    float* gf    = (float*)ws;
    float* gb    = (float*)(ws + gfB);
    char*  fixed = ws + 2 * gfB;
    float* h0    = (float*)fixed;
    float* h1    = (float*)(fixed + 4096000ull);
    float* wp    = (float*)(fixed + 8192000ull);
    float* hs    = (float*)(fixed + 8192000ull + 266240ull);
    float* cs    = (float*)(fixed + 8192000ull + 266240ull + 8000ull);
    int*   order = (int*)  (fixed + 8192000ull + 266240ull + 8000ull + 512000ull);
    int*   cnt   = (int*)  (fixed + 8192000ull + 266240ull + 8000ull + 512000ull + 2048000ull);
    int*   startp= (int*)  (fixed + 8192000ull + 266240ull + 8000ull + 512000ull + 2048000ull + 10240ull);
    int*   cur   = (int*)  (fixed + 8192000ull + 266240ull + 8000ull + 512000ull + 2048000ull + 10240ull + 10272ull);

    // Binning (once) + composed weights
    bin_zero_kernel<<<10, 256, 0, stream>>>(cnt);
    compose_kernel<<<130, 512, 0, stream>>>(
        ccba_W, ccba_b, cdtx_W, cdtx_b, cust_W, cust_b,
        dp_W, dp_b, remit_W, remit_b, Wih0, bih0, bhh0, wp);
    bin_count_kernel<<<dim3(400, 5), 256, 0, stream>>>(
        ccba_ti, cdtx_ti, cust_ti, dp_ti, remit_ti, cnt);
    bin_scan_kernel<<<5, 512, 0, stream>>>(cnt, startp, cur);
    bin_scatter_kernel<<<dim3(400, 5), 256, 0, stream>>>(
        ccba_ti, cdtx_ti, cust_ti, dp_ti, remit_ti, cur, order);

    int first = 1;
    for (int f0 = 0; f0 < TLEN; f0 += tcm) {
        const int len = (TLEN - f0 < tcm) ? (TLEN - f0) : tcm;
        project_chunk_kernel<<<dim3(512, 10), 256, 0, stream>>>(
            ccba_num, ccba_bi, ccba_ti,
            cdtx_num, cdtx_cat, cdtx_tab, cdtx_bi, cdtx_ti,
            cust_num, cust_cat, cust_tab, cust_bi, cust_ti,
            dp_num, dp_cat, dp_tab, dp_bi, dp_ti,
            remit_num, remit_cat, remit_tab, remit_bi, remit_ti,
            wp, order, startp, gf, gb, f0, len, tcm);
        rec_chunk_kernel<<<500, 256, 0, stream>>>(
            gf, gb, Whh0, Whr0, h0, hs, cs, f0, len, tcm, first);
        first = 0;
    }

    lstm1_kernel<<<500, 256, 0, stream>>>(h0, Whh1 ? Wih1 : Wih1, Whh1, Whr1, bih1, bhh1, h1);
    mean_kernel<<<(BATCH * TLEN + 255) / 256, 256, 0, stream>>>((const float2*)h1, out);
}